// Round 10
// baseline (3048.592 us; speedup 1.0000x reference)
//
#include <hip/hip_runtime.h>
#include <math.h>

// ODE-RNN forward: B=512, K=1024, U=16, P=32, H=128, L=32, TD=64
// v11 = v10 (2751us) + v5's wave-private tail phase => 2 barriers/step.
//
// v10 cut barriers 6->3 (win, -270us); its residual: phase Y (jump+RK4+
// stage+lift, ~90 instr) ran on wave0 ONLY while 7 waves idled at barrier
// B, and barrier B existed only to publish wave0's xL. v11 makes phase Y
// redundant per wave (featW/xW/dtW wave-private, y-state replicated, only
// wave0 stores out_ys) -> xL never crosses waves -> barrier B deleted.
// All pieces silicon-proven: wave-private no-barrier tail (v5 passed),
// padded hbuf (v7: conflicts 2e8->4k), DPP reduce 0xB1/0x4E/0x104 (v7/v8),
// packed fp32 pairs (v9: issue->wall 1:1), lgkm-only barriers (v2/v4/v5).
// Hazards: hbufP[rp] writes in iter k+1 happen only after E(k); all reads
// of hbufP[rp] completed before D(k) < E(k). thetaL writes of iter k+1
// happen after D(k+1), which requires every thread past phase Y(k). Same-
// wave LDS write->read (featW/xW/dtW) is in-order per wave (v5/v10 proven).
//
// History: v1 3455; v2 5751 (phase chunking); v3 18063 (2 blocks/CU
// impossible: 245KB weights/block must be register-resident); v4 3610
// (barrier drains/staging latency not the bottleneck); v5 3644; v6 FAIL
// (row_ror direction); v7 4054 (conflicts fixed, scalar math); v8 5257
// (16-wave split -> AGPR shuffle 2.4x issue); v9 3021 (packed pairs);
// v10 2751 (3 barriers, DPP fusion).

typedef float v2f __attribute__((ext_vector_type(2)));

__device__ __forceinline__ v2f mkv2(float a, float b) {
  v2f r; r.x = a; r.y = b; return r;
}

// packed DOT4: float4 v dotted with 2 register pairs (pair base pb)
#define PKD4(acc2, v, w2, pb)                                             \
  acc2 = __builtin_elementwise_fma(mkv2((v).x, (v).y), (w2)[(pb)], acc2); \
  acc2 = __builtin_elementwise_fma(mkv2((v).z, (v).w), (w2)[(pb) + 1], acc2);

__device__ __forceinline__ float sigf(float x) {
  return 1.0f / (1.0f + __expf(-x));
}

__device__ __forceinline__ float tanh_fast(float x) {
  float ax = fabsf(x);
  float e = __expf(2.0f * ax);
  float r = 1.0f - 2.0f / (e + 1.0f);
  return copysignf(r, x);
}

// x + (x cross-lane via DPP), pure VALU pipe.
// 0xB1 quad_perm xor1; 0x4E quad_perm xor2; 0x104 row_shl:4 (dst i <- src
// i+4; valid at row-lanes <12, leaders at row-lanes 0/8).
template <int CTRL>
__device__ __forceinline__ float dpp_add(float x) {
  int s = __float_as_int(x);
  int r = __builtin_amdgcn_update_dpp(s, s, CTRL, 0xF, 0xF, false);
  return x + __int_as_float(r);
}

// LDS-only barrier: drains lgkmcnt but NOT vmcnt (stores/prefetch loads
// stay in flight). Proven v2/v4/v5/v7.
#define BAR()                                            \
  do {                                                   \
    asm volatile("s_waitcnt lgkmcnt(0)" ::: "memory");   \
    __builtin_amdgcn_s_barrier();                        \
    asm volatile("" ::: "memory");                       \
  } while (0)

// padded h index: +4 words after every 32 cols (slice qj starts at 36qj)
#define HP(c) ((c) + 4 * ((c) >> 5))
#define HROW 144  // 128 + 12 pad, 16B multiple

extern "C" __global__ __launch_bounds__(512, 2) void odernn_kernel(
    const float* __restrict__ y0, const float* __restrict__ u_seq,
    const float* __restrict__ dt_seq, const float* __restrict__ y_seq,
    const float* __restrict__ u2y, const float* __restrict__ lift_W,
    const float* __restrict__ lift_b, const float* __restrict__ w_ih,
    const float* __restrict__ w_hh, const float* __restrict__ b_ih,
    const float* __restrict__ b_hh, const float* __restrict__ head_W,
    const float* __restrict__ head_b, const int* __restrict__ tf_p,
    float* __restrict__ out_ys, float* __restrict__ out_th) {
  __shared__ __align__(16) float hbufP[2][2][HROW];  // h dbuf, HP-padded
  __shared__ __align__(16) float xW[8][2][32];       // lifted x, wave-private
  __shared__ __align__(16) float featW[8][2][48];    // [u|y_in], wave-private
  __shared__ float dtW[8][2];                        // dt, wave-private
  __shared__ float thetaL[2][64];                    // shared at barrier E
  __shared__ float liftL[32 * 49];                   // stride 49 conflict-free
  __shared__ float u2yL[512];

  const int t = threadIdx.x;
  const int wv = t >> 6;   // wave 0..7
  const int l = t & 63;    // lane
  const int b0 = blockIdx.x * 2;
  const int j = t >> 2;    // hidden unit 0..127 (4 adjacent lanes per unit)
  const int qj = t & 3;    // col slice: x[8qj..8qj+8) + h[32qj..32qj+32)
  const int ho = t >> 3;   // head output 0..63 (8 adjacent lanes per output)
  const int he = t & 7;    // head col slice: h[16he..16he+16)
  const int tfe = *tf_p;

  // ---- register-resident gate weights as pairs (20 v2f per gate):
  // pairs 0..3 = x-cols 8qj..8qj+8; pairs 4..19 = h-cols 32qj..32qj+32
  v2f wr2[20], wz2[20], wn2[20];
  {
    const int jr = j, jz = j + 128, jn = j + 256;
#pragma unroll
    for (int cc = 0; cc < 8; ++cc) {
      const int c = 8 * qj + cc;
      wr2[cc >> 1][cc & 1] = w_ih[jr * 32 + c];
      wz2[cc >> 1][cc & 1] = w_ih[jz * 32 + c];
      wn2[cc >> 1][cc & 1] = w_ih[jn * 32 + c];
    }
#pragma unroll
    for (int cc = 0; cc < 32; ++cc) {
      const int c = 32 * qj + cc;
      wr2[4 + (cc >> 1)][cc & 1] = w_hh[jr * 128 + c];
      wz2[4 + (cc >> 1)][cc & 1] = w_hh[jz * 128 + c];
      wn2[4 + (cc >> 1)][cc & 1] = w_hh[jn * 128 + c];
    }
  }
  v2f wh2[8];
#pragma unroll
  for (int i = 0; i < 16; ++i)
    wh2[i >> 1][i & 1] = head_W[ho * 128 + 16 * he + i];

  const float bR = b_ih[j] + b_hh[j];
  const float bZ = b_ih[j + 128] + b_hh[j + 128];
  const float bIn = b_ih[j + 256];
  const float bHn = b_hh[j + 256];
  const float hb = head_b[ho];
  const float lb = lift_b[l & 31];

  for (int idx = t; idx < 32 * 48; idx += 512)
    liftL[(idx / 48) * 49 + (idx % 48)] = lift_W[idx];
  u2yL[t] = u2y[t];
  for (int idx = t; idx < 2 * 2 * HROW; idx += 512)
    (&hbufP[0][0][0])[idx] = 0.0f;  // zero both h buffers incl. padding

  float hreg[2] = {0.0f, 0.0f};  // quad-redundant h state for unit j
  // replicated per-wave state: lane l holds y for (bb=l>>5, jj=l&31)
  float yreg = y0[(b0 + (l >> 5)) * 32 + (l & 31)];
  // per-wave prefetch registers (redundant loads; L1-served)
  float upf = 0.0f, dtpf = 0.0f;
  if (l < 32) upf = u_seq[((size_t)(b0 + (l >> 4)) * 1024 + 1) * 16 + (l & 15)];
  if (l >= 32 && l < 34) dtpf = dt_seq[(size_t)(b0 + l - 32) * 1024 + 1];

  // ---- prologue (every wave): stage feat(0), lift x(0) into xW[wv]
  {
    const int bb = l >> 5, jj = l & 31;
    if (l < 32)
      featW[wv][l >> 4][l & 15] =
          u_seq[((size_t)(b0 + (l >> 4)) * 1024 + 0) * 16 + (l & 15)];
    if (l >= 32 && l < 34) dtW[wv][l - 32] = dt_seq[(size_t)(b0 + l - 32) * 1024];
    featW[wv][bb][16 + jj] = yreg;  // k=0: no teacher forcing
    v2f a2 = {0.f, 0.f};
#pragma unroll
    for (int i = 0; i < 48; i += 2)
      a2 = __builtin_elementwise_fma(
          mkv2(featW[wv][bb][i], featW[wv][bb][i + 1]),
          mkv2(liftL[jj * 49 + i], liftL[jj * 49 + i + 1]), a2);
    float acc = a2.x + a2.y + lb;
    xW[wv][bb][jj] = acc * sigf(acc);
  }
  int mtfk = 0;  // k % tfe, incremental
  __syncthreads();  // liftL/u2yL/hbufP-zero visible (once)

  for (int k = 0; k < 1024; ++k) {
    const int rp = k & 1;  // gates read hbufP[rp]=h(k-1); write hbufP[rp^1]

    // ---- phase G: gates (packed) + quad DPP reduce + GRU, all threads
#pragma unroll
    for (int bb = 0; bb < 2; ++bb) {
      v2f aR2 = {0.f, 0.f}, aZ2 = {0.f, 0.f};
      v2f aI2 = {0.f, 0.f}, aN2 = {0.f, 0.f};
      const float4* xv = reinterpret_cast<const float4*>(&xW[wv][bb][8 * qj]);
      {
        float4 v = xv[0];
        PKD4(aR2, v, wr2, 0) PKD4(aZ2, v, wz2, 0) PKD4(aI2, v, wn2, 0)
        v = xv[1];
        PKD4(aR2, v, wr2, 2) PKD4(aZ2, v, wz2, 2) PKD4(aI2, v, wn2, 2)
      }
      const float4* hv =
          reinterpret_cast<const float4*>(&hbufP[rp][bb][36 * qj]);
#pragma unroll
      for (int i = 0; i < 8; ++i) {
        float4 v = hv[i];
        PKD4(aR2, v, wr2, 4 + 2 * i)
        PKD4(aZ2, v, wz2, 4 + 2 * i)
        PKD4(aN2, v, wn2, 4 + 2 * i)
      }
      float aR = aR2.x + aR2.y;
      float aZ = aZ2.x + aZ2.y;
      float aI = aI2.x + aI2.y;
      float aN = aN2.x + aN2.y;
      // quad reduce (xor1, xor2): all 4 lanes end with full sums
      aR = dpp_add<0xB1>(aR); aR = dpp_add<0x4E>(aR);
      aZ = dpp_add<0xB1>(aZ); aZ = dpp_add<0x4E>(aZ);
      aI = dpp_add<0xB1>(aI); aI = dpp_add<0x4E>(aI);
      aN = dpp_add<0xB1>(aN); aN = dpp_add<0x4E>(aN);
      // GRU (quad-redundant, intra-wave); qj==0 writes h
      float r = sigf(aR + bR);
      float z = sigf(aZ + bZ);
      float n = tanh_fast(aI + bIn + r * (aN + bHn));
      float hn = (1.0f - z) * n + z * hreg[bb];
      hreg[bb] = hn;
      if (qj == 0) hbufP[rp ^ 1][bb][HP(j)] = hn;
    }
    BAR();  // D: h(k) visible

    // ---- phase H: head (packed) + 8-lane DPP reduce + theta, all threads
    {
      float s[2];
#pragma unroll
      for (int bb = 0; bb < 2; ++bb) {
        const float4* h4 =
            reinterpret_cast<const float4*>(&hbufP[rp ^ 1][bb][HP(16 * he)]);
        v2f a2 = {0.f, 0.f};
#pragma unroll
        for (int i = 0; i < 4; ++i) {
          float4 v = h4[i];
          PKD4(a2, v, wh2, 2 * i)
        }
        float a = a2.x + a2.y;
        a = dpp_add<0xB1>(a); a = dpp_add<0x4E>(a); a = dpp_add<0x104>(a);
        s[bb] = a;
      }
      if (he == 0) {  // row-lanes 0/8: full 8-lane sum valid after row_shl:4
#pragma unroll
        for (int bb = 0; bb < 2; ++bb) {
          float th = 0.001f + 1.999f * sigf(s[bb] + hb);
          thetaL[bb][ho] = th;
          out_th[((size_t)(b0 + bb) * 1024 + k) * 64 + ho] = th;
        }
      }
    }
    BAR();  // E: thetaL visible

    // ---- phase Y (EVERY wave, redundant): jump + RK4 + stage(k+1) + lift
    {
      const int bb = l >> 5, jj = l & 31;
      v2f y2 = {0.f, 0.f};
#pragma unroll
      for (int i = 0; i < 16; i += 2)
        y2 = __builtin_elementwise_fma(
            mkv2(featW[wv][bb][i], featW[wv][bb][i + 1]),
            mkv2(u2yL[i * 32 + jj], u2yL[(i + 1) * 32 + jj]), y2);
      float y = yreg + y2.x + y2.y;
      float a = thetaL[bb][jj];
      float b2 = thetaL[bb][32 + jj];
      float hdt = dtW[wv][bb];
      float k1 = b2 - a * y;
      float k2 = b2 - a * (y + 0.5f * hdt * k1);
      float k3 = b2 - a * (y + 0.5f * hdt * k2);
      float k4 = b2 - a * (y + hdt * k3);
      y += hdt * (1.0f / 6.0f) * (k1 + 2.0f * k2 + 2.0f * k3 + k4);
      yreg = y;
      if (wv == 0) out_ys[((size_t)(b0 + bb) * 1024 + k) * 32 + jj] = y;
      // stage k+1 from prefetch regs (same wave; LDS in-order per wave)
      if (l < 32) featW[wv][l >> 4][l & 15] = upf;
      if (l >= 32 && l < 34) dtW[wv][l - 32] = dtpf;
      {
        const int kn = (k + 2 < 1024) ? k + 2 : 1023;
        if (l < 32)
          upf = u_seq[((size_t)(b0 + (l >> 4)) * 1024 + kn) * 16 + (l & 15)];
        if (l >= 32 && l < 34)
          dtpf = dt_seq[(size_t)(b0 + l - 32) * 1024 + kn];
      }
      float yin = y;
      if (mtfk == tfe - 1)  // (k+1)%tfe==0 -> y_tf(k+1)=y_seq[k] (1 in 50)
        yin = y_seq[((size_t)(b0 + bb) * 1024 + k) * 32 + jj];
      featW[wv][bb][16 + jj] = yin;
      // lift x(k+1) into wave-private xW (consumed by same wave's gates)
      v2f a2 = {0.f, 0.f};
#pragma unroll
      for (int i = 0; i < 48; i += 2)
        a2 = __builtin_elementwise_fma(
            mkv2(featW[wv][bb][i], featW[wv][bb][i + 1]),
            mkv2(liftL[jj * 49 + i], liftL[jj * 49 + i + 1]), a2);
      float acc = a2.x + a2.y + lb;
      xW[wv][bb][jj] = acc * sigf(acc);
    }
    mtfk = (mtfk + 1 == tfe) ? 0 : mtfk + 1;
    // no barrier: xW/featW/dtW wave-private; hbufP[rp] rewrite happens only
    // after E(k); thetaL rewrite only after D(k+1).
  }
}

extern "C" void kernel_launch(void* const* d_in, const int* in_sizes, int n_in,
                              void* d_out, int out_size, void* d_ws,
                              size_t ws_size, hipStream_t stream) {
  (void)in_sizes; (void)n_in; (void)out_size; (void)d_ws; (void)ws_size;
  const float* y0     = (const float*)d_in[0];
  const float* u_seq  = (const float*)d_in[1];
  const float* dt_seq = (const float*)d_in[2];
  const float* y_seq  = (const float*)d_in[3];
  const float* u2y    = (const float*)d_in[4];
  const float* lift_W = (const float*)d_in[5];
  const float* lift_b = (const float*)d_in[6];
  const float* w_ih   = (const float*)d_in[7];
  const float* w_hh   = (const float*)d_in[8];
  const float* b_ih   = (const float*)d_in[9];
  const float* b_hh   = (const float*)d_in[10];
  const float* head_W = (const float*)d_in[11];
  const float* head_b = (const float*)d_in[12];
  const int*   tf_p   = (const int*)d_in[13];

  float* out_ys = (float*)d_out;
  float* out_th = out_ys + (size_t)512 * 1024 * 32;

  odernn_kernel<<<dim3(256), dim3(512), 0, stream>>>(
      y0, u_seq, dt_seq, y_seq, u2y, lift_W, lift_b, w_ih, w_hh, b_ih, b_hh,
      head_W, head_b, tf_p, out_ys, out_th);
}